// Round 1
// baseline (99.661 us; speedup 1.0000x reference)
//
#include <hip/hip_runtime.h>
#include <hip/hip_bf16.h>

// Problem constants
#define B_N   8192
#define OBS   128
#define HID   512
#define HEADS 4
#define VSZ   256
#define NU    64
#define TOPK  8
#define NOPT  16

typedef __bf16 bf16_t;
typedef __bf16 bf16x8 __attribute__((ext_vector_type(8)));
typedef float  f32x4  __attribute__((ext_vector_type(4)));

// Workspace layout (bytes)
#define OFF_WEFF 0u                         // 512*256*4 = 524288
#define OFF_C    524288u                    // 256*4   = 1024
#define OFF_D    525312u                    // 16*256*4 = 16384
#define OFF_A    541696u                    // 16*4
#define OFF_MT   544768u                    // 256*128*2 = 65536 (bf16, transposed M)
#define OFF_XB   610304u                    // 8192*128*2 = 2097152 (bf16 x)
// total ~2.6 MB

// ---------------------------------------------------------------------------
// Kernel 1: W_eff[j][v] = 0.25 * sum_head value_w[j][head*256 + v]
// grid 512, block 256
__global__ void k_weff(const float* __restrict__ vw, float* __restrict__ weff) {
    int j = blockIdx.x, v = threadIdx.x;
    const float* r = vw + j * (HEADS * VSZ);
    weff[j * VSZ + v] = 0.25f * (r[v] + r[v + VSZ] + r[v + 2 * VSZ] + r[v + 3 * VSZ]);
}

// ---------------------------------------------------------------------------
// Kernel 2: M^T (bf16)  and  c[v] = pre_fc_b @ W_eff
// block k in [0,128]: k<128 -> row k of M via pre_fc_w; k==128 -> c via pre_fc_b
// grid 129, block 256
__global__ void k_m(const float* __restrict__ pw, const float* __restrict__ pb,
                    const float* __restrict__ weff, bf16_t* __restrict__ mt,
                    float* __restrict__ c) {
    int k = blockIdx.x, v = threadIdx.x;
    const float* wr = (k < OBS) ? (pw + k * HID) : pb;
    float a0 = 0.f, a1 = 0.f, a2 = 0.f, a3 = 0.f;
    #pragma unroll 4
    for (int j = 0; j < HID; j += 4) {
        a0 += wr[j + 0] * weff[(j + 0) * VSZ + v];
        a1 += wr[j + 1] * weff[(j + 1) * VSZ + v];
        a2 += wr[j + 2] * weff[(j + 2) * VSZ + v];
        a3 += wr[j + 3] * weff[(j + 3) * VSZ + v];
    }
    float acc = (a0 + a1) + (a2 + a3);
    if (k < OBS) mt[v * OBS + k] = (bf16_t)acc;   // Mt[v][k] = M[k][v]
    else         c[v] = acc;
}

// ---------------------------------------------------------------------------
// Kernel 3: A[opt] = (1/64) * sum_{n in top8} sigmoid(p_w[opt][n] + p_b[n])
//           D[opt][v] = A[opt]*c[v] + 0.125*b_eff[v]
// one block, 1024 threads (16 waves; wave w handles option w)
__global__ void k_coef(const float* __restrict__ p_w, const float* __restrict__ p_b,
                       const float* __restrict__ vb, const float* __restrict__ c,
                       float* __restrict__ A, float* __restrict__ D) {
    __shared__ float sA[NOPT];
    int tid  = threadIdx.x;
    int lane = tid & 63;
    int opt  = tid >> 6;

    float cur = p_w[opt * NU + lane] + p_b[lane];
    float sum = 0.f;
    #pragma unroll
    for (int t = 0; t < TOPK; ++t) {
        float m = cur;
        #pragma unroll
        for (int off = 32; off >= 1; off >>= 1)
            m = fmaxf(m, __shfl_xor(m, off));
        sum += 1.f / (1.f + expf(-m));
        unsigned long long b = __ballot(cur == m);
        int first = __ffsll(b) - 1;           // lowest index -> jax tie-break
        if (lane == first) cur = -1e30f;
    }
    if (lane == 0) { sA[opt] = sum * (1.f / NU); A[opt] = sA[opt]; }
    __syncthreads();

    if (tid < VSZ) {
        int v = tid;
        float be = 0.25f * (vb[v] + vb[v + VSZ] + vb[v + 2 * VSZ] + vb[v + 3 * VSZ]);
        float cv = c[v];
        #pragma unroll
        for (int o = 0; o < NOPT; ++o)
            D[o * VSZ + v] = sA[o] * cv + 0.125f * be;
    }
}

// ---------------------------------------------------------------------------
// Kernel 4: x (f32) -> xb (bf16), row-major 8192x128
// grid 512, block 256, 8 elements/thread
__global__ void k_cast(const float* __restrict__ x, bf16_t* __restrict__ xb) {
    int i = (blockIdx.x * 256 + threadIdx.x) * 8;
    f32x4 a = *(const f32x4*)(x + i);
    f32x4 b = *(const f32x4*)(x + i + 4);
    bf16x8 o;
    o[0] = (bf16_t)a[0]; o[1] = (bf16_t)a[1]; o[2] = (bf16_t)a[2]; o[3] = (bf16_t)a[3];
    o[4] = (bf16_t)b[0]; o[5] = (bf16_t)b[1]; o[6] = (bf16_t)b[2]; o[7] = (bf16_t)b[3];
    *(bf16x8*)(xb + i) = o;
}

// ---------------------------------------------------------------------------
// Kernel 5: out[b][v] = A[opt[b]] * (x @ M)[b][v] + D[opt[b]][v]
// MFMA 16x16x32 bf16. Block = 256 thr = 4 waves. Wave tile: 16 rows x 64 cols.
// Block tile: 64 rows x 64 cols. grid (8192/64, 256/64) = (128, 4).
__launch_bounds__(256)
__global__ void k_main(const bf16_t* __restrict__ xb, const bf16_t* __restrict__ mt,
                       const int* __restrict__ opt, const float* __restrict__ A,
                       const float* __restrict__ D, float* __restrict__ out) {
    int wave = threadIdx.x >> 6;
    int lane = threadIdx.x & 63;
    int r0   = blockIdx.x * 64 + wave * 16;
    int c0   = blockIdx.y * 64;
    int mrow = lane & 15;   // m (A rows) / n (B cols) index
    int quad = lane >> 4;   // 0..3

    f32x4 acc0 = {0.f, 0.f, 0.f, 0.f};
    f32x4 acc1 = {0.f, 0.f, 0.f, 0.f};
    f32x4 acc2 = {0.f, 0.f, 0.f, 0.f};
    f32x4 acc3 = {0.f, 0.f, 0.f, 0.f};

    const bf16_t* xa = xb + (r0 + mrow) * OBS + quad * 8;        // A frag base
    const bf16_t* mb = mt + (c0 + mrow) * OBS + quad * 8;        // B frag base (Mt[v][k])

    #pragma unroll
    for (int kt = 0; kt < 4; ++kt) {
        bf16x8 a  = *(const bf16x8*)(xa + kt * 32);
        bf16x8 b0 = *(const bf16x8*)(mb + kt * 32);
        bf16x8 b1 = *(const bf16x8*)(mb + 16 * OBS + kt * 32);
        bf16x8 b2 = *(const bf16x8*)(mb + 32 * OBS + kt * 32);
        bf16x8 b3 = *(const bf16x8*)(mb + 48 * OBS + kt * 32);
        acc0 = __builtin_amdgcn_mfma_f32_16x16x32_bf16(a, b0, acc0, 0, 0, 0);
        acc1 = __builtin_amdgcn_mfma_f32_16x16x32_bf16(a, b1, acc1, 0, 0, 0);
        acc2 = __builtin_amdgcn_mfma_f32_16x16x32_bf16(a, b2, acc2, 0, 0, 0);
        acc3 = __builtin_amdgcn_mfma_f32_16x16x32_bf16(a, b3, acc3, 0, 0, 0);
    }

    // Epilogue: C/D layout col=lane&15, row=quad*4+reg
    int col = c0 + mrow;
    #pragma unroll
    for (int r = 0; r < 4; ++r) {
        int row = r0 + quad * 4 + r;
        int o = opt[row];
        float a = A[o];
        const float* Dr = D + o * VSZ;
        out[row * VSZ + col +  0] = a * acc0[r] + Dr[col +  0];
        out[row * VSZ + col + 16] = a * acc1[r] + Dr[col + 16];
        out[row * VSZ + col + 32] = a * acc2[r] + Dr[col + 32];
        out[row * VSZ + col + 48] = a * acc3[r] + Dr[col + 48];
    }
}

// ---------------------------------------------------------------------------
extern "C" void kernel_launch(void* const* d_in, const int* in_sizes, int n_in,
                              void* d_out, int out_size, void* d_ws, size_t ws_size,
                              hipStream_t stream) {
    const float* x        = (const float*)d_in[0];
    const int*   option   = (const int*)  d_in[1];
    const float* pre_fc_w = (const float*)d_in[2];
    const float* pre_fc_b = (const float*)d_in[3];
    const float* value_w  = (const float*)d_in[4];
    const float* value_b  = (const float*)d_in[5];
    const float* p_w      = (const float*)d_in[6];
    const float* p_b      = (const float*)d_in[7];
    float* out = (float*)d_out;

    char* ws = (char*)d_ws;
    float*  weff = (float*) (ws + OFF_WEFF);
    float*  c    = (float*) (ws + OFF_C);
    float*  D    = (float*) (ws + OFF_D);
    float*  A    = (float*) (ws + OFF_A);
    bf16_t* mt   = (bf16_t*)(ws + OFF_MT);
    bf16_t* xbuf = (bf16_t*)(ws + OFF_XB);

    k_weff<<<dim3(HID), dim3(VSZ), 0, stream>>>(value_w, weff);
    k_m   <<<dim3(OBS + 1), dim3(VSZ), 0, stream>>>(pre_fc_w, pre_fc_b, weff, mt, c);
    k_coef<<<dim3(1), dim3(NOPT * 64), 0, stream>>>(p_w, p_b, value_b, c, A, D);
    k_cast<<<dim3(B_N * OBS / (256 * 8)), dim3(256), 0, stream>>>(x, xbuf);
    k_main<<<dim3(B_N / 64, VSZ / 64), dim3(256), 0, stream>>>(xbuf, mt, option, A, D, out);
}

// Round 2
// 97.596 us; speedup vs baseline: 1.0212x; 1.0212x over previous
//
#include <hip/hip_runtime.h>
#include <hip/hip_bf16.h>

// Problem constants
#define B_N   8192
#define OBS   128
#define HID   512
#define HEADS 4
#define VSZ   256
#define NU    64
#define TOPK  8
#define NOPT  16
#define KEXT  160   // GEMM K extended: 128 x-cols + 1 bias col + 31 zero pad

typedef __bf16 bf16_t;
typedef __bf16 bf16x8 __attribute__((ext_vector_type(8)));
typedef float  f32x4  __attribute__((ext_vector_type(4)));

// Workspace layout (bytes)
#define OFF_WEFF 0u         // 512*256*4 = 524288
#define OFF_A    524288u    // 16*4
#define OFF_DP   524352u    // 256*4
#define OFF_MT   525376u    // 256*160*2 = 81920 (bf16 M^T, rows 0..127 = M,
                            //  row 128 = c, rows 129..159 = 0), 16B aligned

// ---------------------------------------------------------------------------
// Kernel 1: blocks 0..511: weff[j][v] = 0.25 * sum_head value_w[j][h*256+v]
//           block 512:     A[opt] (top-8 sigmoid sum / 64) and Dp[v]=0.125*be[v]
__global__ void k_pre(const float* __restrict__ vw, const float* __restrict__ p_w,
                      const float* __restrict__ p_b, const float* __restrict__ vb,
                      float* __restrict__ weff, float* __restrict__ A,
                      float* __restrict__ Dp) {
    if (blockIdx.x < HID) {
        int j = blockIdx.x, v = threadIdx.x;
        const float* r = vw + j * (HEADS * VSZ);
        weff[j * VSZ + v] = 0.25f * (r[v] + r[v + VSZ] + r[v + 2 * VSZ] + r[v + 3 * VSZ]);
        return;
    }
    // A + Dp block. 4 waves; wave w handles options 4w..4w+3.
    int tid  = threadIdx.x;
    int lane = tid & 63;
    int w    = tid >> 6;
    #pragma unroll
    for (int oo = 0; oo < 4; ++oo) {
        int o = w * 4 + oo;
        float cur = p_w[o * NU + lane] + p_b[lane];
        float sum = 0.f;
        #pragma unroll
        for (int t = 0; t < TOPK; ++t) {
            float m = cur;
            #pragma unroll
            for (int off = 32; off >= 1; off >>= 1)
                m = fmaxf(m, __shfl_xor(m, off));
            sum += 1.f / (1.f + expf(-m));
            unsigned long long bal = __ballot(cur == m);
            int first = __ffsll(bal) - 1;      // lowest index: jax tie-break
            if (lane == first) cur = -1e30f;
        }
        if (lane == 0) A[o] = sum * (1.f / NU);
    }
    if (tid < VSZ)
        Dp[tid] = 0.125f * 0.25f * (vb[tid] + vb[tid + VSZ] + vb[tid + 2 * VSZ] + vb[tid + 3 * VSZ]);
}

// ---------------------------------------------------------------------------
// Kernel 2: M^T (bf16, row stride KEXT). Block k (0..159), 1024 threads:
//   4 j-quarters x 256 v, LDS reduce. k<128: M row via pre_fc_w;
//   k==128: c row via pre_fc_b; k>128: zeros.
__global__ void k_mt(const float* __restrict__ pw, const float* __restrict__ pb,
                     const float* __restrict__ weff, bf16_t* __restrict__ mt) {
    int k  = blockIdx.x;
    int v  = threadIdx.x & 255;
    int jq = threadIdx.x >> 8;
    __shared__ float red[1024];
    if (k > 128) {
        if (threadIdx.x < VSZ) mt[v * KEXT + k] = (bf16_t)0.f;
        return;
    }
    const float* wr = (k < OBS) ? (pw + k * HID) : pb;
    const float* wj = wr + jq * 128;
    const float* wf = weff + (jq * 128) * VSZ + v;
    float a0 = 0.f, a1 = 0.f, a2 = 0.f, a3 = 0.f;
    #pragma unroll 4
    for (int j = 0; j < 128; j += 4) {
        a0 += wj[j + 0] * wf[(j + 0) * VSZ];
        a1 += wj[j + 1] * wf[(j + 1) * VSZ];
        a2 += wj[j + 2] * wf[(j + 2) * VSZ];
        a3 += wj[j + 3] * wf[(j + 3) * VSZ];
    }
    red[threadIdx.x] = (a0 + a1) + (a2 + a3);
    __syncthreads();
    if (jq == 0) {
        float s = red[v] + red[v + 256] + red[v + 512] + red[v + 768];
        mt[v * KEXT + k] = (bf16_t)s;
    }
}

// ---------------------------------------------------------------------------
// Kernel 3: out[b][v] = A[opt[b]] * (x' @ M')[b][v] + Dp[v]
// x' = [x | 1 | 0...], M' = [M ; c ; 0...]; K = 160. f32 x converted to bf16
// in-register. MFMA 16x16x32. Block = 4 waves; wave: 16 rows x 128 cols.
// grid (8192/64, 256/128) = (128, 2).
__launch_bounds__(256)
__global__ void k_main(const float* __restrict__ x, const bf16_t* __restrict__ mt,
                       const int* __restrict__ opt, const float* __restrict__ A,
                       const float* __restrict__ Dp, float* __restrict__ out) {
    int wave = threadIdx.x >> 6;
    int lane = threadIdx.x & 63;
    int mrow = lane & 15;
    int quad = lane >> 4;
    int r0   = blockIdx.x * 64 + wave * 16;
    int c0   = blockIdx.y * 128;

    f32x4 acc[8];
    #pragma unroll
    for (int t = 0; t < 8; ++t) acc[t] = (f32x4){0.f, 0.f, 0.f, 0.f};

    const float*  xr = x + (r0 + mrow) * OBS + quad * 8;
    const bf16_t* mb = mt + (c0 + mrow) * KEXT + quad * 8;

    #pragma unroll
    for (int kt = 0; kt < 5; ++kt) {
        bf16x8 a;
        if (kt < 4) {
            f32x4 lo = *(const f32x4*)(xr + kt * 32);
            f32x4 hi = *(const f32x4*)(xr + kt * 32 + 4);
            a[0] = (bf16_t)lo[0]; a[1] = (bf16_t)lo[1];
            a[2] = (bf16_t)lo[2]; a[3] = (bf16_t)lo[3];
            a[4] = (bf16_t)hi[0]; a[5] = (bf16_t)hi[1];
            a[6] = (bf16_t)hi[2]; a[7] = (bf16_t)hi[3];
        } else {
            #pragma unroll
            for (int j = 0; j < 8; ++j) a[j] = (bf16_t)0.f;
            if (quad == 0) a[0] = (bf16_t)1.0f;   // k=128: the bias column
        }
        #pragma unroll
        for (int t = 0; t < 8; ++t) {
            bf16x8 b = *(const bf16x8*)(mb + t * 16 * KEXT + kt * 32);
            acc[t] = __builtin_amdgcn_mfma_f32_16x16x32_bf16(a, b, acc[t], 0, 0, 0);
        }
    }

    // C/D layout: col=lane&15, row=quad*4+reg
    #pragma unroll
    for (int r = 0; r < 4; ++r) {
        int row = r0 + quad * 4 + r;
        float av = A[opt[row]];
        float* orow = out + row * VSZ;
        #pragma unroll
        for (int t = 0; t < 8; ++t) {
            int col = c0 + t * 16 + mrow;
            orow[col] = av * acc[t][r] + Dp[col];
        }
    }
}

// ---------------------------------------------------------------------------
extern "C" void kernel_launch(void* const* d_in, const int* in_sizes, int n_in,
                              void* d_out, int out_size, void* d_ws, size_t ws_size,
                              hipStream_t stream) {
    const float* x        = (const float*)d_in[0];
    const int*   option   = (const int*)  d_in[1];
    const float* pre_fc_w = (const float*)d_in[2];
    const float* pre_fc_b = (const float*)d_in[3];
    const float* value_w  = (const float*)d_in[4];
    const float* value_b  = (const float*)d_in[5];
    const float* p_w      = (const float*)d_in[6];
    const float* p_b      = (const float*)d_in[7];
    float* out = (float*)d_out;

    char* ws = (char*)d_ws;
    float*  weff = (float*) (ws + OFF_WEFF);
    float*  A    = (float*) (ws + OFF_A);
    float*  Dp   = (float*) (ws + OFF_DP);
    bf16_t* mt   = (bf16_t*)(ws + OFF_MT);

    k_pre <<<dim3(HID + 1), dim3(VSZ), 0, stream>>>(value_w, p_w, p_b, value_b, weff, A, Dp);
    k_mt  <<<dim3(KEXT), dim3(1024), 0, stream>>>(pre_fc_w, pre_fc_b, weff, mt);
    k_main<<<dim3(B_N / 64, VSZ / 128), dim3(256), 0, stream>>>(x, mt, option, A, Dp, out);
}